// Round 4
// baseline (1604.665 us; speedup 1.0000x reference)
//
#include <hip/hip_runtime.h>
#include <stdint.h>

#define L_LAYERS 4
#define BATCH 8
#define PHH 24
#define PWW 24
#define PP (PHH*PWW)        // 576
#define DD 1024
#define ROWS (BATCH*PP)     // 4608
#define OH 336
#define OW 336
#define NTILES 72           // 4608/64  (64-col max groups)
#define TT 36               // 4608/128 (128x128 tiles per dim)
#define NPAIRS (TT*(TT+1)/2)  // 666 upper-triangle tiles
#define NCOMBO 12           // 3 radii x 4 layers
#define PRESCALE 1024.0f    // fp8 quant prescale (power of 2, exact)
#define INV_PRESCALE2_X2 (1.f/524288.f)   // 2 / PRESCALE^2

typedef __attribute__((ext_vector_type(8))) int i32x8;
typedef __attribute__((ext_vector_type(4))) int i32x4;
typedef __attribute__((ext_vector_type(4))) float f32x4;

// float -> bf16 round-to-nearest-even (raw bits)
__device__ __forceinline__ unsigned int f2bf(float f) {
  unsigned int u = __float_as_uint(f);
  return (u + 0x7FFFu + ((u >> 16) & 1u)) >> 16;
}

// async global->LDS, 16B per lane. LDS dest must be wave-uniform base + lane*16.
__device__ __forceinline__ void async16(const void* g, void* l) {
  __builtin_amdgcn_global_load_lds(
      (const __attribute__((address_space(1))) void*)(size_t)(uintptr_t)g,
      (__attribute__((address_space(3))) void*)(uint32_t)(uintptr_t)l,
      16, 0, 0);
}

// ---------------------------------------------------------------------------
// Kernel 1a: vertical pool. For each (l,row): v3 = sum rows py-1..py+1,
// v5 = sum rows py-2..py+2 (zero-pad), stored as bf16. 128 thr x 8 dims.
// ---------------------------------------------------------------------------
__global__ __launch_bounds__(128) void vpool_kernel(
    const float* __restrict__ feat,      // [L][B][PP][DD]
    unsigned short* __restrict__ c3,     // [L][ROWS][DD] bf16 bits
    unsigned short* __restrict__ c5) {   // [L][ROWS][DD] bf16 bits
  const int row = blockIdx.x;            // b*576 + p
  const int l = blockIdx.y;
  const int b = row / PP;
  const int p = row % PP;
  const int py = p / PWW;
  const int t = threadIdx.x;
  const int d0 = t * 8;
  const float* base = feat + ((size_t)l * BATCH + b) * PP * DD + (size_t)p * DD + d0;

  float v3[8] = {0,0,0,0,0,0,0,0}, v5[8] = {0,0,0,0,0,0,0,0};
  #pragma unroll
  for (int dy = -2; dy <= 2; ++dy) {
    int yy = py + dy; if (yy < 0 || yy >= PHH) continue;
    const float4 a = *(const float4*)(base + (size_t)dy * PWW * DD);
    const float4 c = *(const float4*)(base + (size_t)dy * PWW * DD + 4);
    v5[0]+=a.x; v5[1]+=a.y; v5[2]+=a.z; v5[3]+=a.w;
    v5[4]+=c.x; v5[5]+=c.y; v5[6]+=c.z; v5[7]+=c.w;
    if (dy >= -1 && dy <= 1) {
      v3[0]+=a.x; v3[1]+=a.y; v3[2]+=a.z; v3[3]+=a.w;
      v3[4]+=c.x; v3[5]+=c.y; v3[6]+=c.z; v3[7]+=c.w;
    }
  }
  const size_t idx = ((size_t)l * ROWS + row) * DD + d0;
  uint4 o;
  o.x = f2bf(v3[0]) | (f2bf(v3[1]) << 16);
  o.y = f2bf(v3[2]) | (f2bf(v3[3]) << 16);
  o.z = f2bf(v3[4]) | (f2bf(v3[5]) << 16);
  o.w = f2bf(v3[6]) | (f2bf(v3[7]) << 16);
  *(uint4*)&c3[idx] = o;
  o.x = f2bf(v5[0]) | (f2bf(v5[1]) << 16);
  o.y = f2bf(v5[2]) | (f2bf(v5[3]) << 16);
  o.z = f2bf(v5[4]) | (f2bf(v5[5]) << 16);
  o.w = f2bf(v5[6]) | (f2bf(v5[7]) << 16);
  *(uint4*)&c5[idx] = o;
}

// expand bf16 pair (packed in uint) and accumulate
#define ACC2(dst, i, w) { dst[i] += __uint_as_float((w) << 16); \
                          dst[i+1] += __uint_as_float((w) & 0xFFFF0000u); }

// ---------------------------------------------------------------------------
// Kernel 1b: horizontal pool + L2-normalize + fp8(e4m3) quantize (x PRESCALE).
// s1 = center feat row; s3 = sum of 3 c3 cols; s5 = sum of 5 c5 cols.
// 128 thr x 8 dims; block-wide norm reduction (2 waves).
// ---------------------------------------------------------------------------
__global__ __launch_bounds__(128) void hpool_kernel(
    const float* __restrict__ feat,
    const unsigned short* __restrict__ c3,
    const unsigned short* __restrict__ c5,
    unsigned char* __restrict__ nf_all) {   // [NCOMBO][ROWS][DD] fp8
  const int row = blockIdx.x;
  const int l = blockIdx.y;
  const int b = row / PP;
  const int p = row % PP;
  const int px = p % PWW;
  const int t = threadIdx.x;
  const int d0 = t * 8;

  float s1[8], s3[8] = {0,0,0,0,0,0,0,0}, s5[8] = {0,0,0,0,0,0,0,0};
  {
    const float* fb = feat + ((size_t)l * BATCH + b) * PP * DD + (size_t)p * DD + d0;
    const float4 a = *(const float4*)fb;
    const float4 c = *(const float4*)(fb + 4);
    s1[0]=a.x; s1[1]=a.y; s1[2]=a.z; s1[3]=a.w;
    s1[4]=c.x; s1[5]=c.y; s1[6]=c.z; s1[7]=c.w;
  }
  const size_t cbase = ((size_t)l * ROWS + row) * DD + d0;
  #pragma unroll
  for (int dx = -2; dx <= 2; ++dx) {
    int xx = px + dx; if (xx < 0 || xx >= PWW) continue;
    const uint4 w5 = *(const uint4*)&c5[cbase + (size_t)dx * DD];
    ACC2(s5, 0, w5.x); ACC2(s5, 2, w5.y); ACC2(s5, 4, w5.z); ACC2(s5, 6, w5.w);
    if (dx >= -1 && dx <= 1) {
      const uint4 w3 = *(const uint4*)&c3[cbase + (size_t)dx * DD];
      ACC2(s3, 0, w3.x); ACC2(s3, 2, w3.y); ACC2(s3, 4, w3.z); ACC2(s3, 6, w3.w);
    }
  }
  float q1 = 0, q3 = 0, q5 = 0;
  #pragma unroll
  for (int i = 0; i < 8; ++i) {
    q1 += s1[i]*s1[i]; q3 += s3[i]*s3[i]; q5 += s5[i]*s5[i];
  }
  #pragma unroll
  for (int off = 32; off > 0; off >>= 1) {
    q1 += __shfl_down(q1, off);
    q3 += __shfl_down(q3, off);
    q5 += __shfl_down(q5, off);
  }
  __shared__ float red[2][3];
  const int lane = t & 63, w = t >> 6;
  if (lane == 0) { red[w][0] = q1; red[w][1] = q3; red[w][2] = q5; }
  __syncthreads();
  const float rn1 = rsqrtf(red[0][0] + red[1][0]) * PRESCALE;
  const float rn3 = rsqrtf(red[0][1] + red[1][1]) * PRESCALE;
  const float rn5 = rsqrtf(red[0][2] + red[1][2]) * PRESCALE;

  const size_t rowoff = (size_t)row * DD + d0;
  unsigned int lo, hi;
  uint2 o;
  lo = __builtin_amdgcn_cvt_pk_fp8_f32(s1[0]*rn1, s1[1]*rn1, 0, false);
  lo = __builtin_amdgcn_cvt_pk_fp8_f32(s1[2]*rn1, s1[3]*rn1, lo, true);
  hi = __builtin_amdgcn_cvt_pk_fp8_f32(s1[4]*rn1, s1[5]*rn1, 0, false);
  hi = __builtin_amdgcn_cvt_pk_fp8_f32(s1[6]*rn1, s1[7]*rn1, hi, true);
  o.x = lo; o.y = hi;
  *(uint2*)(nf_all + (size_t)(0*L_LAYERS + l) * ROWS * DD + rowoff) = o;
  lo = __builtin_amdgcn_cvt_pk_fp8_f32(s3[0]*rn3, s3[1]*rn3, 0, false);
  lo = __builtin_amdgcn_cvt_pk_fp8_f32(s3[2]*rn3, s3[3]*rn3, lo, true);
  hi = __builtin_amdgcn_cvt_pk_fp8_f32(s3[4]*rn3, s3[5]*rn3, 0, false);
  hi = __builtin_amdgcn_cvt_pk_fp8_f32(s3[6]*rn3, s3[7]*rn3, hi, true);
  o.x = lo; o.y = hi;
  *(uint2*)(nf_all + (size_t)(1*L_LAYERS + l) * ROWS * DD + rowoff) = o;
  lo = __builtin_amdgcn_cvt_pk_fp8_f32(s5[0]*rn5, s5[1]*rn5, 0, false);
  lo = __builtin_amdgcn_cvt_pk_fp8_f32(s5[2]*rn5, s5[3]*rn5, lo, true);
  hi = __builtin_amdgcn_cvt_pk_fp8_f32(s5[4]*rn5, s5[5]*rn5, 0, false);
  hi = __builtin_amdgcn_cvt_pk_fp8_f32(s5[6]*rn5, s5[7]*rn5, hi, true);
  o.x = lo; o.y = hi;
  *(uint2*)(nf_all + (size_t)(2*L_LAYERS + l) * ROWS * DD + rowoff) = o;
}

// ---------------------------------------------------------------------------
// Kernel 2: symmetric Gram GEMM, MX-fp8 (e4m3, unity E8M0 scales), all 12
// combos in one dispatch. grid = (NPAIRS, NCOMBO); upper-triangle 128x128
// tiles; same-image tile pairs dead (c==b masked) -> exit. K-tile = 128 fp8.
// mfma_scale_f32_16x16x128_f8f6f4; fused row-max + col-max epilogue.
// ---------------------------------------------------------------------------
__global__ __launch_bounds__(256, 3) void gemm_max_kernel(
    const unsigned char* __restrict__ nf_all,   // [NCOMBO][ROWS][DD] fp8
    float* __restrict__ part) {                 // [NCOMBO][ROWS][NTILES]
  // decode linear block id -> upper-triangle (it, jt), it <= jt
  int it = 0, rem = blockIdx.x;
  while (rem >= TT - it) { rem -= TT - it; ++it; }
  const int jt = it + rem;
  const int row0 = it * 128;
  const int col0 = jt * 128;

  // dead-tile check: both tiles fully inside the same image -> never read
  {
    const bool inA = (row0 / PP) == ((row0 + 127) / PP);
    const bool inB = (col0 / PP) == ((col0 + 127) / PP);
    if (inA && inB && (row0 / PP) == (col0 / PP)) return;
  }

  __shared__ unsigned char As[128 * 128];
  __shared__ unsigned char Bs[128 * 128];

  const int t = threadIdx.x;
  const int lane = t & 63;
  const int wave = t >> 6;
  const int wm = wave >> 1;    // row half (64 rows)
  const int wn = wave & 1;     // col half (64 cols)
  const int combo = blockIdx.y;

  const unsigned char* nf = nf_all + (size_t)combo * ROWS * DD;
  float* partialL = part + (size_t)combo * ROWS * NTILES;

  const f32x4 zero = {0.f, 0.f, 0.f, 0.f};
  f32x4 acc[4][4];
  #pragma unroll
  for (int m = 0; m < 4; ++m)
    #pragma unroll
    for (int n = 0; n < 4; ++n) acc[m][n] = zero;

  const unsigned char* gA = nf + (size_t)row0 * DD;
  const unsigned char* gB = nf + (size_t)col0 * DD;

  for (int kt = 0; kt < DD / 128; ++kt) {
    const int k0 = kt * 128;
    // 128 rows x 128 B each = 1024 16B-chunks per matrix; chunk c: row=c>>3,
    // slot j=c&7 holds global k-chunk j ^ (row&7)  (XOR swizzle)
    #pragma unroll
    for (int i = 0; i < 4; ++i) {
      int c = i * 256 + t;
      int row = c >> 3, j = c & 7;
      int g = j ^ (row & 7);
      async16(gA + (size_t)row * DD + k0 + g * 16, &As[c * 16]);
    }
    #pragma unroll
    for (int i = 0; i < 4; ++i) {
      int c = i * 256 + t;
      int row = c >> 3, j = c & 7;
      int g = j ^ (row & 7);
      async16(gB + (size_t)row * DD + k0 + g * 16, &Bs[c * 16]);
    }
    __syncthreads();   // drains vmcnt (global_load_lds) + barrier
    const int q2 = (lane >> 4) << 1;   // first of the lane's two 16B chunks
    i32x8 af[4];
    #pragma unroll
    for (int m = 0; m < 4; ++m) {
      int r = wm * 64 + m * 16 + (lane & 15);
      int c0 = q2 ^ (r & 7);
      i32x4 lo = *(const i32x4*)&As[r * 128 + (c0 << 4)];
      i32x4 hi = *(const i32x4*)&As[r * 128 + ((c0 ^ 1) << 4)];
      af[m] = (i32x8){lo[0], lo[1], lo[2], lo[3], hi[0], hi[1], hi[2], hi[3]};
    }
    #pragma unroll
    for (int n = 0; n < 4; ++n) {
      int r = wn * 64 + n * 16 + (lane & 15);
      int c0 = q2 ^ (r & 7);
      i32x4 lo = *(const i32x4*)&Bs[r * 128 + (c0 << 4)];
      i32x4 hi = *(const i32x4*)&Bs[r * 128 + ((c0 ^ 1) << 4)];
      i32x8 bf = (i32x8){lo[0], lo[1], lo[2], lo[3], hi[0], hi[1], hi[2], hi[3]};
      #pragma unroll
      for (int m = 0; m < 4; ++m)
        acc[m][n] = __builtin_amdgcn_mfma_scale_f32_16x16x128_f8f6f4(
            af[m], bf, acc[m][n], 0, 0, 0, 0x7F7F7F7F, 0, 0x7F7F7F7F);
    }
    __syncthreads();
  }

  // C/D layout: col = lane&15, row = (lane>>4)*4 + reg (shape-determined)
  // Row-max over this wave's 64 cols (group 2*jt+wn).
  #pragma unroll
  for (int m = 0; m < 4; ++m) {
    #pragma unroll
    for (int g = 0; g < 4; ++g) {
      float v = fmaxf(fmaxf(acc[m][0][g], acc[m][1][g]),
                      fmaxf(acc[m][2][g], acc[m][3][g]));
      v = fmaxf(v, __shfl_xor(v, 1));
      v = fmaxf(v, __shfl_xor(v, 2));
      v = fmaxf(v, __shfl_xor(v, 4));
      v = fmaxf(v, __shfl_xor(v, 8));
      if ((lane & 15) == 0) {
        int row = row0 + wm * 64 + m * 16 + (lane >> 4) * 4 + g;
        partialL[(size_t)row * NTILES + 2 * jt + wn] = v;
      }
    }
  }
  // Col-max over this wave's 64 rows (group 2*it+wm), written transposed.
  if (it != jt) {
    #pragma unroll
    for (int n = 0; n < 4; ++n) {
      float v = -1e30f;
      #pragma unroll
      for (int m = 0; m < 4; ++m)
        #pragma unroll
        for (int g = 0; g < 4; ++g) v = fmaxf(v, acc[m][n][g]);
      v = fmaxf(v, __shfl_xor(v, 16));
      v = fmaxf(v, __shfl_xor(v, 32));
      if (lane < 16) {
        int col = col0 + wn * 64 + n * 16 + lane;
        partialL[(size_t)col * NTILES + 2 * it + wm] = v;
      }
    }
  }
}

// ---------------------------------------------------------------------------
// Kernel 3: per row: for each of 12 combos, max over 9 q-groups per image c,
// d-transform (undo fp8 prescale), top-2 smallest over c != b; sum -> scores.
// ---------------------------------------------------------------------------
__global__ __launch_bounds__(256) void reduce_topk_kernel(
    const float* __restrict__ part,      // [NCOMBO][ROWS][NTILES]
    float* __restrict__ scores) {        // [ROWS]
  const int row = blockIdx.x * 256 + threadIdx.x;
  if (row >= ROWS) return;
  const int b = row / PP;
  float sum = 0.f;
  for (int k = 0; k < NCOMBO; ++k) {
    const float* pr = part + ((size_t)k * ROWS + row) * NTILES;
    float d1 = 1e30f, d2 = 1e30f;
    #pragma unroll
    for (int c = 0; c < BATCH; ++c) {
      if (c == b) continue;
      float md = pr[c * 9];
      #pragma unroll
      for (int q = 1; q < 9; ++q) md = fmaxf(md, pr[c * 9 + q]);
      float d = sqrtf(fmaxf(2.f - md * INV_PRESCALE2_X2, 0.f));
      if (d < d1) { d2 = d1; d1 = d; }
      else if (d < d2) { d2 = d; }
    }
    sum += 0.5f * (d1 + d2);
  }
  scores[row] = sum;
}

// ---------------------------------------------------------------------------
// Kernel 4: scores_image[b] = max_p scores[b,p] / 12
// ---------------------------------------------------------------------------
__global__ __launch_bounds__(256) void image_max_kernel(
    const float* __restrict__ scores, float* __restrict__ out) {
  const int b = blockIdx.x;
  const int t = threadIdx.x;
  float m = -1e30f;
  for (int p = t; p < PP; p += 256) m = fmaxf(m, scores[b * PP + p]);
  #pragma unroll
  for (int off = 32; off > 0; off >>= 1) m = fmaxf(m, __shfl_down(m, off));
  __shared__ float red[4];
  if ((t & 63) == 0) red[t >> 6] = m;
  __syncthreads();
  if (t == 0)
    out[b] = fmaxf(fmaxf(red[0], red[1]), fmaxf(red[2], red[3])) * (1.f / 12.f);
}

// ---------------------------------------------------------------------------
// Kernel 5: bilinear (align_corners) 24x24 -> 336x336, scale 1/12
// ---------------------------------------------------------------------------
__global__ __launch_bounds__(256) void upsample_kernel(
    const float* __restrict__ scores, float* __restrict__ out) {
  const int idx = blockIdx.x * 256 + threadIdx.x;
  if (idx >= BATCH * OH * OW) return;
  const int b = idx / (OH * OW);
  const int rem = idx % (OH * OW);
  const int y = rem / OW, x = rem % OW;
  const float sc = (float)(23.0 / 335.0);
  const float ys = y * sc, xs = x * sc;
  const int y0 = (int)floorf(ys), x0 = (int)floorf(xs);
  const float wy = ys - (float)y0, wx = xs - (float)x0;
  const int y1 = min(y0 + 1, PHH - 1), x1 = min(x0 + 1, PWW - 1);
  const float* sb = scores + b * PP;
  const float f00 = sb[y0 * PWW + x0], f01 = sb[y0 * PWW + x1];
  const float f10 = sb[y1 * PWW + x0], f11 = sb[y1 * PWW + x1];
  const float v = f00 * (1.f - wy) * (1.f - wx) + f01 * (1.f - wy) * wx +
                  f10 * wy * (1.f - wx) + f11 * wy * wx;
  out[8 + idx] = v * (1.f / 12.f);
}

// ---------------------------------------------------------------------------
extern "C" void kernel_launch(void* const* d_in, const int* in_sizes, int n_in,
                              void* d_out, int out_size, void* d_ws, size_t ws_size,
                              hipStream_t stream) {
  const float* feat = (const float*)d_in[0];     // [4][8][576][1024] f32
  float* out = (float*)d_out;                    // [8] ++ [8][336][336]
  char* ws = (char*)d_ws;

  // workspace layout (~148 MB of ~302 MB)
  const size_t NF_BYTES   = (size_t)NCOMBO * ROWS * DD;            // 56,623,104 (fp8)
  const size_t PART_BYTES = (size_t)NCOMBO * ROWS * NTILES * 4;    // 15,925,248
  const size_t SCR_BYTES  = (size_t)ROWS * 4;                      //     18,432
  const size_t C_BYTES    = (size_t)L_LAYERS * ROWS * DD * 2;      // 37,748,736
  unsigned char*  nf_all = (unsigned char*)ws;
  float*          part   = (float*)(ws + NF_BYTES);
  float*          scr    = (float*)(ws + NF_BYTES + PART_BYTES);
  unsigned short* c3     = (unsigned short*)(ws + NF_BYTES + PART_BYTES + SCR_BYTES);
  unsigned short* c5     = (unsigned short*)(ws + NF_BYTES + PART_BYTES + SCR_BYTES + C_BYTES);

  vpool_kernel<<<dim3(ROWS, L_LAYERS), 128, 0, stream>>>(feat, c3, c5);
  hpool_kernel<<<dim3(ROWS, L_LAYERS), 128, 0, stream>>>(feat, c3, c5, nf_all);
  gemm_max_kernel<<<dim3(NPAIRS, NCOMBO), 256, 0, stream>>>(nf_all, part);
  reduce_topk_kernel<<<(ROWS + 255) / 256, 256, 0, stream>>>(part, scr);
  image_max_kernel<<<BATCH, 256, 0, stream>>>(scr, out);
  upsample_kernel<<<(BATCH * OH * OW + 255) / 256, 256, 0, stream>>>(scr, out);
}

// Round 5
// 489.989 us; speedup vs baseline: 3.2749x; 3.2749x over previous
//
#include <hip/hip_runtime.h>
#include <stdint.h>

#define L_LAYERS 4
#define BATCH 8
#define PHH 24
#define PWW 24
#define PP (PHH*PWW)        // 576
#define DD 1024
#define ROWS (BATCH*PP)     // 4608
#define OH 336
#define OW 336
#define NTILES 72           // 4608/64  (64-col max groups)
#define TT 36               // 4608/128 (128x128 tiles per dim)
#define NPAIRS (TT*(TT+1)/2)  // 666 upper-triangle tiles
#define NCOMBO 12           // 3 radii x 4 layers

typedef __attribute__((ext_vector_type(8))) __bf16 bf16x8;
typedef __attribute__((ext_vector_type(4))) float f32x4;

// float -> bf16 round-to-nearest-even (raw bits)
__device__ __forceinline__ unsigned int f2bf(float f) {
  unsigned int u = __float_as_uint(f);
  return (u + 0x7FFFu + ((u >> 16) & 1u)) >> 16;
}

// async global->LDS, 16B per lane. LDS dest must be wave-uniform base + lane*16.
__device__ __forceinline__ void async16(const void* g, void* l) {
  __builtin_amdgcn_global_load_lds(
      (const __attribute__((address_space(1))) void*)(size_t)(uintptr_t)g,
      (__attribute__((address_space(3))) void*)(uint32_t)(uintptr_t)l,
      16, 0, 0);
}

// ---------------------------------------------------------------------------
// Kernel 1a: sliding-window vertical pool (reads feat exactly once).
// grid = (16 d-chunks, BATCH, L_LAYERS*2 y-halves); 256 threads.
// Ring of 5 rows x 24 px x 64 dims (f32) in LDS; emits c3 (3-row vertical
// sum) and c5 (5-row vertical sum) as bf16, zero-padded in y.
// ---------------------------------------------------------------------------
__global__ __launch_bounds__(256) void vpool_ring_kernel(
    const float* __restrict__ feat,      // [L][B][PP][DD]
    unsigned short* __restrict__ c3,     // [L][ROWS][DD] bf16 bits
    unsigned short* __restrict__ c5) {   // [L][ROWS][DD] bf16 bits
  const int dch = blockIdx.x;            // 64-dim chunk
  const int b = blockIdx.y;
  const int l = blockIdx.z >> 1;
  const int half = blockIdx.z & 1;
  const int py0 = half * 12, py1 = py0 + 11;
  const int t = threadIdx.x;
  const int pxg = t >> 5;                // 0..7
  const int d2 = t & 31;                 // float2 index within 64-dim chunk

  __shared__ float ring[5][24 * 64];

  const float* fb = feat + ((size_t)l * BATCH + b) * PP * DD + dch * 64 + d2 * 2;

  // preload rows py0-2 .. py0+1 (skip OOB)
  for (int yy = py0 - 2; yy <= py0 + 1; ++yy) {
    if (yy < 0) continue;
    #pragma unroll
    for (int i = 0; i < 3; ++i) {
      int px = i * 8 + pxg;
      *(float2*)&ring[yy % 5][px * 64 + d2 * 2] =
          *(const float2*)(fb + (size_t)(yy * PWW + px) * DD);
    }
  }
  for (int py = py0; py <= py1; ++py) {
    const int yl = py + 2;
    if (yl < PHH) {
      __syncthreads();   // slot (py+2)%5 == (py-3)%5 was read last iteration
      #pragma unroll
      for (int i = 0; i < 3; ++i) {
        int px = i * 8 + pxg;
        *(float2*)&ring[yl % 5][px * 64 + d2 * 2] =
            *(const float2*)(fb + (size_t)(yl * PWW + px) * DD);
      }
    }
    __syncthreads();
    #pragma unroll
    for (int i = 0; i < 3; ++i) {
      int px = i * 8 + pxg;
      float s3x = 0.f, s3y = 0.f, s5x = 0.f, s5y = 0.f;
      #pragma unroll
      for (int dy = -2; dy <= 2; ++dy) {
        int yy = py + dy;
        if (yy < 0 || yy >= PHH) continue;
        float2 v = *(const float2*)&ring[yy % 5][px * 64 + d2 * 2];
        s5x += v.x; s5y += v.y;
        if (dy >= -1 && dy <= 1) { s3x += v.x; s3y += v.y; }
      }
      const size_t idx =
          ((size_t)l * ROWS + b * PP + py * PWW + px) * DD + dch * 64 + d2 * 2;
      *(unsigned int*)&c3[idx] = f2bf(s3x) | (f2bf(s3y) << 16);
      *(unsigned int*)&c5[idx] = f2bf(s5x) | (f2bf(s5y) << 16);
    }
  }
}

// expand bf16 pair (packed in uint) and accumulate
#define ACC2(dst, i, w) { dst[i] += __uint_as_float((w) << 16); \
                          dst[i+1] += __uint_as_float((w) & 0xFFFF0000u); }

// ---------------------------------------------------------------------------
// Kernel 1b: horizontal pool + L2-normalize + bf16 cast.
// s1 = center feat row; s3 = sum of 3 c3 cols; s5 = sum of 5 c5 cols.
// 128 thr x 8 dims; block-wide norm reduction (2 waves).
// ---------------------------------------------------------------------------
__global__ __launch_bounds__(128) void hpool_kernel(
    const float* __restrict__ feat,
    const unsigned short* __restrict__ c3,
    const unsigned short* __restrict__ c5,
    unsigned short* __restrict__ nf_all) {  // [NCOMBO][ROWS][DD] bf16
  const int row = blockIdx.x;
  const int l = blockIdx.y;
  const int b = row / PP;
  const int p = row % PP;
  const int px = p % PWW;
  const int t = threadIdx.x;
  const int d0 = t * 8;

  float s1[8], s3[8] = {0,0,0,0,0,0,0,0}, s5[8] = {0,0,0,0,0,0,0,0};
  {
    const float* fb = feat + ((size_t)l * BATCH + b) * PP * DD + (size_t)p * DD + d0;
    const float4 a = *(const float4*)fb;
    const float4 c = *(const float4*)(fb + 4);
    s1[0]=a.x; s1[1]=a.y; s1[2]=a.z; s1[3]=a.w;
    s1[4]=c.x; s1[5]=c.y; s1[6]=c.z; s1[7]=c.w;
  }
  const size_t cbase = ((size_t)l * ROWS + row) * DD + d0;
  #pragma unroll
  for (int dx = -2; dx <= 2; ++dx) {
    int xx = px + dx; if (xx < 0 || xx >= PWW) continue;
    const uint4 w5 = *(const uint4*)&c5[cbase + (size_t)dx * DD];
    ACC2(s5, 0, w5.x); ACC2(s5, 2, w5.y); ACC2(s5, 4, w5.z); ACC2(s5, 6, w5.w);
    if (dx >= -1 && dx <= 1) {
      const uint4 w3 = *(const uint4*)&c3[cbase + (size_t)dx * DD];
      ACC2(s3, 0, w3.x); ACC2(s3, 2, w3.y); ACC2(s3, 4, w3.z); ACC2(s3, 6, w3.w);
    }
  }
  float q1 = 0, q3 = 0, q5 = 0;
  #pragma unroll
  for (int i = 0; i < 8; ++i) {
    q1 += s1[i]*s1[i]; q3 += s3[i]*s3[i]; q5 += s5[i]*s5[i];
  }
  #pragma unroll
  for (int off = 32; off > 0; off >>= 1) {
    q1 += __shfl_down(q1, off);
    q3 += __shfl_down(q3, off);
    q5 += __shfl_down(q5, off);
  }
  __shared__ float red[2][3];
  const int lane = t & 63, w = t >> 6;
  if (lane == 0) { red[w][0] = q1; red[w][1] = q3; red[w][2] = q5; }
  __syncthreads();
  const float rn1 = rsqrtf(red[0][0] + red[1][0]);
  const float rn3 = rsqrtf(red[0][1] + red[1][1]);
  const float rn5 = rsqrtf(red[0][2] + red[1][2]);

  const size_t rowoff = (size_t)row * DD + d0;
  uint4 o;
  o.x = f2bf(s1[0]*rn1) | (f2bf(s1[1]*rn1) << 16);
  o.y = f2bf(s1[2]*rn1) | (f2bf(s1[3]*rn1) << 16);
  o.z = f2bf(s1[4]*rn1) | (f2bf(s1[5]*rn1) << 16);
  o.w = f2bf(s1[6]*rn1) | (f2bf(s1[7]*rn1) << 16);
  *(uint4*)(nf_all + (size_t)(0*L_LAYERS + l) * ROWS * DD + rowoff) = o;
  o.x = f2bf(s3[0]*rn3) | (f2bf(s3[1]*rn3) << 16);
  o.y = f2bf(s3[2]*rn3) | (f2bf(s3[3]*rn3) << 16);
  o.z = f2bf(s3[4]*rn3) | (f2bf(s3[5]*rn3) << 16);
  o.w = f2bf(s3[6]*rn3) | (f2bf(s3[7]*rn3) << 16);
  *(uint4*)(nf_all + (size_t)(1*L_LAYERS + l) * ROWS * DD + rowoff) = o;
  o.x = f2bf(s5[0]*rn5) | (f2bf(s5[1]*rn5) << 16);
  o.y = f2bf(s5[2]*rn5) | (f2bf(s5[3]*rn5) << 16);
  o.z = f2bf(s5[4]*rn5) | (f2bf(s5[5]*rn5) << 16);
  o.w = f2bf(s5[6]*rn5) | (f2bf(s5[7]*rn5) << 16);
  *(uint4*)(nf_all + (size_t)(2*L_LAYERS + l) * ROWS * DD + rowoff) = o;
}

// ---------------------------------------------------------------------------
// Kernel 2: symmetric Gram GEMM (bf16, R3-exact: measured 261 us, 0 LDS
// conflicts, MfmaUtil 41%). All 12 combos in one dispatch; upper-triangle
// 128x128 tiles; same-image tile pairs dead (c==b masked) -> exit.
// Fused row-max per 64-col group + col-max (transposed tile's row-max).
// ---------------------------------------------------------------------------
__global__ __launch_bounds__(256, 3) void gemm_max_kernel(
    const unsigned short* __restrict__ nf_all,  // [NCOMBO][ROWS][DD]
    float* __restrict__ part) {                 // [NCOMBO][ROWS][NTILES]
  // decode linear block id -> upper-triangle (it, jt), it <= jt
  int it = 0, rem = blockIdx.x;
  while (rem >= TT - it) { rem -= TT - it; ++it; }
  const int jt = it + rem;
  const int row0 = it * 128;
  const int col0 = jt * 128;

  // dead-tile check: both tiles fully inside the same image -> never read
  {
    const bool inA = (row0 / PP) == ((row0 + 127) / PP);
    const bool inB = (col0 / PP) == ((col0 + 127) / PP);
    if (inA && inB && (row0 / PP) == (col0 / PP)) return;
  }

  __shared__ unsigned short As[128 * 64];
  __shared__ unsigned short Bs[128 * 64];

  const int t = threadIdx.x;
  const int lane = t & 63;
  const int wave = t >> 6;
  const int wm = wave >> 1;    // row half (64 rows)
  const int wn = wave & 1;     // col half (64 cols)
  const int combo = blockIdx.y;

  const unsigned short* nf = nf_all + (size_t)combo * ROWS * DD;
  float* partialL = part + (size_t)combo * ROWS * NTILES;

  const f32x4 zero = {0.f, 0.f, 0.f, 0.f};
  f32x4 acc[4][4];
  #pragma unroll
  for (int m = 0; m < 4; ++m)
    #pragma unroll
    for (int n = 0; n < 4; ++n) acc[m][n] = zero;

  const unsigned short* gA = nf + (size_t)row0 * DD;
  const unsigned short* gB = nf + (size_t)col0 * DD;

  for (int kt = 0; kt < DD / 64; ++kt) {
    const int k0 = kt * 64;
    // 128 rows x 64 K each = 1024 16B-chunks per matrix; chunk c: row=c>>3,
    // slot j=c&7 holds global k-chunk j ^ (row&7)  (XOR swizzle)
    #pragma unroll
    for (int i = 0; i < 4; ++i) {
      int c = i * 256 + t;
      int row = c >> 3, j = c & 7;
      int g = j ^ (row & 7);
      async16(gA + (size_t)row * DD + k0 + g * 8, &As[c * 8]);
    }
    #pragma unroll
    for (int i = 0; i < 4; ++i) {
      int c = i * 256 + t;
      int row = c >> 3, j = c & 7;
      int g = j ^ (row & 7);
      async16(gB + (size_t)row * DD + k0 + g * 8, &Bs[c * 8]);
    }
    __syncthreads();   // drains vmcnt (global_load_lds) + barrier
    #pragma unroll
    for (int s = 0; s < 2; ++s) {
      const int kc = s * 4 + (lane >> 4);   // 16B chunk index within 64-wide K
      bf16x8 af[4], bfr[4];
      #pragma unroll
      for (int m = 0; m < 4; ++m) {
        int row = wm * 64 + m * 16 + (lane & 15);
        af[m] = *(const bf16x8*)&As[row * 64 + ((kc ^ (row & 7)) << 3)];
      }
      #pragma unroll
      for (int n = 0; n < 4; ++n) {
        int brow = wn * 64 + n * 16 + (lane & 15);
        bfr[n] = *(const bf16x8*)&Bs[brow * 64 + ((kc ^ (brow & 7)) << 3)];
      }
      #pragma unroll
      for (int m = 0; m < 4; ++m)
        #pragma unroll
        for (int n = 0; n < 4; ++n)
          acc[m][n] = __builtin_amdgcn_mfma_f32_16x16x32_bf16(af[m], bfr[n], acc[m][n], 0, 0, 0);
    }
    __syncthreads();
  }

  // C/D layout: col = lane&15, row = (lane>>4)*4 + reg  [m89]
  // Row-max over this wave's 64 cols (group 2*jt+wn).
  #pragma unroll
  for (int m = 0; m < 4; ++m) {
    #pragma unroll
    for (int g = 0; g < 4; ++g) {
      float v = fmaxf(fmaxf(acc[m][0][g], acc[m][1][g]),
                      fmaxf(acc[m][2][g], acc[m][3][g]));
      v = fmaxf(v, __shfl_xor(v, 1));
      v = fmaxf(v, __shfl_xor(v, 2));
      v = fmaxf(v, __shfl_xor(v, 4));
      v = fmaxf(v, __shfl_xor(v, 8));
      if ((lane & 15) == 0) {
        int row = row0 + wm * 64 + m * 16 + (lane >> 4) * 4 + g;
        partialL[(size_t)row * NTILES + 2 * jt + wn] = v;
      }
    }
  }
  // Col-max over this wave's 64 rows (group 2*it+wm), written transposed.
  if (it != jt) {
    #pragma unroll
    for (int n = 0; n < 4; ++n) {
      float v = -1e30f;
      #pragma unroll
      for (int m = 0; m < 4; ++m)
        #pragma unroll
        for (int g = 0; g < 4; ++g) v = fmaxf(v, acc[m][n][g]);
      v = fmaxf(v, __shfl_xor(v, 16));
      v = fmaxf(v, __shfl_xor(v, 32));
      if (lane < 16) {
        int col = col0 + wn * 64 + n * 16 + lane;
        partialL[(size_t)col * NTILES + 2 * it + wm] = v;
      }
    }
  }
}

// ---------------------------------------------------------------------------
// Kernel 3: per row: for each of 12 combos, max over 9 q-groups per image c,
// d-transform, top-2 smallest over c != b; sum over combos -> scores[row].
// ---------------------------------------------------------------------------
__global__ __launch_bounds__(256) void reduce_topk_kernel(
    const float* __restrict__ part,      // [NCOMBO][ROWS][NTILES]
    float* __restrict__ scores) {        // [ROWS]
  const int row = blockIdx.x * 256 + threadIdx.x;
  if (row >= ROWS) return;
  const int b = row / PP;
  float sum = 0.f;
  for (int k = 0; k < NCOMBO; ++k) {
    const float* pr = part + ((size_t)k * ROWS + row) * NTILES;
    float d1 = 1e30f, d2 = 1e30f;
    #pragma unroll
    for (int c = 0; c < BATCH; ++c) {
      if (c == b) continue;
      float md = pr[c * 9];
      #pragma unroll
      for (int q = 1; q < 9; ++q) md = fmaxf(md, pr[c * 9 + q]);
      float d = sqrtf(fmaxf(2.f - 2.f * md, 0.f));
      if (d < d1) { d2 = d1; d1 = d; }
      else if (d < d2) { d2 = d; }
    }
    sum += 0.5f * (d1 + d2);
  }
  scores[row] = sum;
}

// ---------------------------------------------------------------------------
// Kernel 4: scores_image[b] = max_p scores[b,p] / 12
// ---------------------------------------------------------------------------
__global__ __launch_bounds__(256) void image_max_kernel(
    const float* __restrict__ scores, float* __restrict__ out) {
  const int b = blockIdx.x;
  const int t = threadIdx.x;
  float m = -1e30f;
  for (int p = t; p < PP; p += 256) m = fmaxf(m, scores[b * PP + p]);
  #pragma unroll
  for (int off = 32; off > 0; off >>= 1) m = fmaxf(m, __shfl_down(m, off));
  __shared__ float red[4];
  if ((t & 63) == 0) red[t >> 6] = m;
  __syncthreads();
  if (t == 0)
    out[b] = fmaxf(fmaxf(red[0], red[1]), fmaxf(red[2], red[3])) * (1.f / 12.f);
}

// ---------------------------------------------------------------------------
// Kernel 5: bilinear (align_corners) 24x24 -> 336x336, scale 1/12
// ---------------------------------------------------------------------------
__global__ __launch_bounds__(256) void upsample_kernel(
    const float* __restrict__ scores, float* __restrict__ out) {
  const int idx = blockIdx.x * 256 + threadIdx.x;
  if (idx >= BATCH * OH * OW) return;
  const int b = idx / (OH * OW);
  const int rem = idx % (OH * OW);
  const int y = rem / OW, x = rem % OW;
  const float sc = (float)(23.0 / 335.0);
  const float ys = y * sc, xs = x * sc;
  const int y0 = (int)floorf(ys), x0 = (int)floorf(xs);
  const float wy = ys - (float)y0, wx = xs - (float)x0;
  const int y1 = min(y0 + 1, PHH - 1), x1 = min(x0 + 1, PWW - 1);
  const float* sb = scores + b * PP;
  const float f00 = sb[y0 * PWW + x0], f01 = sb[y0 * PWW + x1];
  const float f10 = sb[y1 * PWW + x0], f11 = sb[y1 * PWW + x1];
  const float v = f00 * (1.f - wy) * (1.f - wx) + f01 * (1.f - wy) * wx +
                  f10 * wy * (1.f - wx) + f11 * wy * wx;
  out[8 + idx] = v * (1.f / 12.f);
}

// ---------------------------------------------------------------------------
extern "C" void kernel_launch(void* const* d_in, const int* in_sizes, int n_in,
                              void* d_out, int out_size, void* d_ws, size_t ws_size,
                              hipStream_t stream) {
  const float* feat = (const float*)d_in[0];     // [4][8][576][1024] f32
  float* out = (float*)d_out;                    // [8] ++ [8][336][336]
  char* ws = (char*)d_ws;

  // workspace layout (~205 MB)
  const size_t NF_BYTES   = (size_t)NCOMBO * ROWS * DD * 2;        // 113,246,208 (bf16)
  const size_t PART_BYTES = (size_t)NCOMBO * ROWS * NTILES * 4;    //  15,925,248
  const size_t SCR_BYTES  = (size_t)ROWS * 4;                      //      18,432
  const size_t C_BYTES    = (size_t)L_LAYERS * ROWS * DD * 2;      //  37,748,736
  unsigned short* nf_all = (unsigned short*)ws;
  float*          part   = (float*)(ws + NF_BYTES);
  float*          scr    = (float*)(ws + NF_BYTES + PART_BYTES);
  unsigned short* c3     = (unsigned short*)(ws + NF_BYTES + PART_BYTES + SCR_BYTES);
  unsigned short* c5     = (unsigned short*)(ws + NF_BYTES + PART_BYTES + SCR_BYTES + C_BYTES);

  vpool_ring_kernel<<<dim3(16, BATCH, L_LAYERS * 2), 256, 0, stream>>>(feat, c3, c5);
  hpool_kernel<<<dim3(ROWS, L_LAYERS), 128, 0, stream>>>(feat, c3, c5, nf_all);
  gemm_max_kernel<<<dim3(NPAIRS, NCOMBO), 256, 0, stream>>>(nf_all, part);
  reduce_topk_kernel<<<(ROWS + 255) / 256, 256, 0, stream>>>(part, scr);
  image_max_kernel<<<BATCH, 256, 0, stream>>>(scr, out);
  upsample_kernel<<<(BATCH * OH * OW + 255) / 256, 256, 0, stream>>>(scr, out);
}